// Round 2
// baseline (364.884 us; speedup 1.0000x reference)
//
#include <hip/hip_runtime.h>

typedef __attribute__((ext_vector_type(8))) short bf16x8;
typedef __attribute__((ext_vector_type(4))) float f32x4;

__device__ __forceinline__ unsigned short f2bf(float f) {
    unsigned int u = __builtin_bit_cast(unsigned int, f);
    u += 0x7fff + ((u >> 16) & 1);
    return (unsigned short)(u >> 16);
}

// ---------------------------------------------------------------------------
// Kernel 0: Wt[m][c][k] = W_m[k][c] * scale_m  (bf16)  m: 0=q (scaled), 1=k, 2=v
// scale_q = 0.125 * log2(e)  -> softmax runs in exp2 domain downstream.
// grid: 48 blocks (m*16 + kchunk), 256 threads.
// ---------------------------------------------------------------------------
__global__ __launch_bounds__(256) void wt_kernel(
    const float* __restrict__ Wk, const float* __restrict__ Wq,
    const float* __restrict__ Wv, unsigned short* __restrict__ Wt)
{
    __shared__ float ws[64][65];
    const int m = blockIdx.x >> 4, kc = blockIdx.x & 15;
    const float* W = (m == 0) ? Wq : (m == 1) ? Wk : Wv;
    const float scale = (m == 0) ? 0.18033688011112042f : 1.0f;
    const int tid = threadIdx.x;
    #pragma unroll
    for (int r = 0; r < 16; ++r) {
        int idx = r * 256 + tid;
        ws[idx >> 6][idx & 63] = W[(kc * 64 + (idx >> 6)) * 64 + (idx & 63)] * scale;
    }
    __syncthreads();
    const int c = tid >> 2, k4 = (tid & 3) * 16;
    bf16x8 o0, o1;
    #pragma unroll
    for (int jj = 0; jj < 8; ++jj) o0[jj] = (short)f2bf(ws[k4 + jj][c]);
    #pragma unroll
    for (int jj = 0; jj < 8; ++jj) o1[jj] = (short)f2bf(ws[k4 + 8 + jj][c]);
    unsigned short* dst = Wt + ((size_t)m * 64 + c) * 1024 + kc * 64 + k4;
    *(bf16x8*)dst = o0;
    *(bf16x8*)(dst + 8) = o1;
}

// ---------------------------------------------------------------------------
// Kernel 1: projections, one wave per 16 rows, no LDS, no barriers.
// qw/kw row-major [16384][64] bf16; vT transposed [b][64][4096] bf16.
// ---------------------------------------------------------------------------
__global__ __launch_bounds__(256) void proj_kernel(
    const float* __restrict__ x, const unsigned short* __restrict__ Wt,
    unsigned short* __restrict__ qw, unsigned short* __restrict__ kw,
    unsigned short* __restrict__ vT)
{
    const int tid = threadIdx.x;
    const int gw = blockIdx.x * 4 + (tid >> 6);   // 0..1023
    const int l = tid & 63;
    const int xr = l & 15, g = l >> 4;
    const int row0 = gw * 16;

    const float* xp = x + (size_t)(row0 + xr) * 1024 + 8 * g;

    f32x4 acc[3][4];
    #pragma unroll
    for (int m = 0; m < 3; ++m)
        #pragma unroll
        for (int t = 0; t < 4; ++t) { f32x4 z = {0.f, 0.f, 0.f, 0.f}; acc[m][t] = z; }

    for (int s = 0; s < 32; ++s) {
        float4 xa = *(const float4*)(xp + 32 * s);
        float4 xb = *(const float4*)(xp + 32 * s + 4);
        bf16x8 a;
        a[0] = (short)f2bf(xa.x); a[1] = (short)f2bf(xa.y);
        a[2] = (short)f2bf(xa.z); a[3] = (short)f2bf(xa.w);
        a[4] = (short)f2bf(xb.x); a[5] = (short)f2bf(xb.y);
        a[6] = (short)f2bf(xb.z); a[7] = (short)f2bf(xb.w);
        #pragma unroll
        for (int m = 0; m < 3; ++m)
            #pragma unroll
            for (int t = 0; t < 4; ++t) {
                bf16x8 bfr = *(const bf16x8*)(Wt + ((size_t)m * 64 + 16 * t + xr) * 1024 + 32 * s + 8 * g);
                acc[m][t] = __builtin_amdgcn_mfma_f32_16x16x32_bf16(a, bfr, acc[m][t], 0, 0, 0);
            }
    }

    const int b = row0 >> 12;
    #pragma unroll
    for (int t = 0; t < 4; ++t)
        #pragma unroll
        for (int i = 0; i < 4; ++i) {
            const int row = row0 + 4 * g + i;
            const int col = xr + 16 * t;
            qw[(size_t)row * 64 + col] = f2bf(acc[0][t][i]);
            kw[(size_t)row * 64 + col] = f2bf(acc[1][t][i]);
            vT[((size_t)b * 64 + col) * 4096 + (row & 4095)] = f2bf(acc[2][t][i]);
        }
}

// ---------------------------------------------------------------------------
// Kernel 2: flash attention, one wave per 16 q-rows. K/V direct from L2
// (no staging, no barriers). Per-wave LDS bounce for P only (stride 72:
// 16B-aligned b128 reads, bank-balanced).
// ---------------------------------------------------------------------------
__global__ __launch_bounds__(256) void attn_kernel(
    const unsigned short* __restrict__ qw, const unsigned short* __restrict__ kw,
    const unsigned short* __restrict__ vT, float* __restrict__ out)
{
    __shared__ unsigned short Ps[4][16][72];
    const int tid = threadIdx.x;
    const int w = tid >> 6, l = tid & 63;
    const int gw = blockIdx.x * 4 + w;            // 0..1023
    const int b = gw >> 8, j = gw & 255;          // q rows [16j, 16j+16)
    const int xr = l & 15, g = l >> 4;
    const size_t base = (size_t)b * 4096;
    const int qrow = j * 16;

    bf16x8 aq[2];
    #pragma unroll
    for (int h = 0; h < 2; ++h)
        aq[h] = *(const bf16x8*)(qw + (base + qrow + xr) * 64 + 32 * h + 8 * g);

    f32x4 accO[4];
    #pragma unroll
    for (int t = 0; t < 4; ++t) { f32x4 z = {0.f, 0.f, 0.f, 0.f}; accO[t] = z; }
    f32x4 mrow = {-1e30f, -1e30f, -1e30f, -1e30f};
    f32x4 lsum = {0.f, 0.f, 0.f, 0.f};

    const int nt = (j >> 2) + 1;
    const unsigned short* kb = kw + base * 64;
    const unsigned short* vb = vT + base * 64;    // == vT + b*64*4096

    for (int it = 0; it < nt; ++it) {
        const int k0 = it * 64;

        // S = Q K^T  (16 rows x 64 keys), exp2-scaled domain
        f32x4 s[4];
        #pragma unroll
        for (int t = 0; t < 4; ++t) {
            f32x4 z = {0.f, 0.f, 0.f, 0.f};
            s[t] = z;
            #pragma unroll
            for (int h = 0; h < 2; ++h) {
                bf16x8 bk = *(const bf16x8*)(kb + (size_t)(k0 + xr + 16 * t) * 64 + 32 * h + 8 * g);
                s[t] = __builtin_amdgcn_mfma_f32_16x16x32_bf16(aq[h], bk, s[t], 0, 0, 0);
            }
        }

        // causal mask — only the (single) diagonal tile is partial
        if (it == nt - 1) {
            #pragma unroll
            for (int t = 0; t < 4; ++t)
                #pragma unroll
                for (int i = 0; i < 4; ++i) {
                    int key = k0 + xr + 16 * t;
                    int row = qrow + 4 * g + i;
                    if (key > row) s[t][i] = -1e30f;
                }
        }

        // row max (within 16-lane group)
        f32x4 tmax = s[0];
        #pragma unroll
        for (int t = 1; t < 4; ++t)
            #pragma unroll
            for (int i = 0; i < 4; ++i) tmax[i] = fmaxf(tmax[i], s[t][i]);
        #pragma unroll
        for (int off = 1; off < 16; off <<= 1)
            #pragma unroll
            for (int i = 0; i < 4; ++i)
                tmax[i] = fmaxf(tmax[i], __shfl_xor(tmax[i], off, 64));

        f32x4 mnew, fac;
        #pragma unroll
        for (int i = 0; i < 4; ++i) {
            mnew[i] = fmaxf(mrow[i], tmax[i]);
            fac[i]  = exp2f(mrow[i] - mnew[i]);
        }

        // P = exp2(S - mnew): bounce D-layout -> A-layout through per-wave LDS
        f32x4 psum = {0.f, 0.f, 0.f, 0.f};
        #pragma unroll
        for (int t = 0; t < 4; ++t)
            #pragma unroll
            for (int i = 0; i < 4; ++i) {
                float p = exp2f(s[t][i] - mnew[i]);
                psum[i] += p;
                Ps[w][4 * g + i][xr + 16 * t] = f2bf(p);
            }
        #pragma unroll
        for (int off = 1; off < 16; off <<= 1)
            #pragma unroll
            for (int i = 0; i < 4; ++i)
                psum[i] += __shfl_xor(psum[i], off, 64);

        #pragma unroll
        for (int i = 0; i < 4; ++i) {
            lsum[i] = lsum[i] * fac[i] + psum[i];
            mrow[i] = mnew[i];
        }
        #pragma unroll
        for (int t = 0; t < 4; ++t)
            #pragma unroll
            for (int i = 0; i < 4; ++i) accO[t][i] *= fac[i];

        // O += P V   (wave-local LDS dependency: lgkmcnt-ordered, no barrier)
        #pragma unroll
        for (int h = 0; h < 2; ++h) {
            bf16x8 pa = *(const bf16x8*)&Ps[w][xr][32 * h + 8 * g];
            #pragma unroll
            for (int t = 0; t < 4; ++t) {
                bf16x8 bv = *(const bf16x8*)(vb + (size_t)(xr + 16 * t) * 4096 + k0 + 32 * h + 8 * g);
                accO[t] = __builtin_amdgcn_mfma_f32_16x16x32_bf16(pa, bv, accO[t], 0, 0, 0);
            }
        }
    }

    #pragma unroll
    for (int t = 0; t < 4; ++t)
        #pragma unroll
        for (int i = 0; i < 4; ++i)
            out[(base + qrow + 4 * g + i) * 64 + xr + 16 * t] = accO[t][i] / lsum[i];
}

extern "C" void kernel_launch(void* const* d_in, const int* in_sizes, int n_in,
                              void* d_out, int out_size, void* d_ws, size_t ws_size,
                              hipStream_t stream) {
    // setup_inputs order: x, Wk, Wq, Wv
    const float* x  = (const float*)d_in[0];
    const float* Wk = (const float*)d_in[1];
    const float* Wq = (const float*)d_in[2];
    const float* Wv = (const float*)d_in[3];
    float* out = (float*)d_out;

    unsigned short* Wt = (unsigned short*)d_ws;          // [3][64][1024] bf16
    unsigned short* qw = Wt + (size_t)3 * 64 * 1024;     // [16384][64]
    unsigned short* kw = qw + (size_t)16384 * 64;        // [16384][64]
    unsigned short* vT = kw + (size_t)16384 * 64;        // [4][64][4096]

    hipLaunchKernelGGL(wt_kernel, dim3(48), dim3(256), 0, stream, Wk, Wq, Wv, Wt);
    hipLaunchKernelGGL(proj_kernel, dim3(256), dim3(256), 0, stream, x, Wt, qw, kw, vT);
    hipLaunchKernelGGL(attn_kernel, dim3(256), dim3(256), 0, stream, qw, kw, vT, out);
}

// Round 3
// 146.957 us; speedup vs baseline: 2.4829x; 2.4829x over previous
//
#include <hip/hip_runtime.h>

typedef __attribute__((ext_vector_type(8))) short bf16x8;
typedef __attribute__((ext_vector_type(4))) float f32x4;

#define DI __device__ __forceinline__

DI unsigned short f2bf(float f) {
    unsigned int u = __builtin_bit_cast(unsigned int, f);
    u += 0x7fff + ((u >> 16) & 1);
    return (unsigned short)(u >> 16);
}

DI void gl_lds16(const void* g, void* l) {
    __builtin_amdgcn_global_load_lds(
        (const __attribute__((address_space(1))) unsigned int*)g,
        (__attribute__((address_space(3))) unsigned int*)l, 16, 0, 0);
}

// ---------------------------------------------------------------------------
// Kernel 0: Wt[m][c][k] = W_m[k][c] * scale_m (bf16). m: 0=q(scaled),1=k,2=v
// scale_q = 0.125 * log2(e) -> softmax in exp2 domain downstream.
// ---------------------------------------------------------------------------
__global__ __launch_bounds__(256) void wt_kernel(
    const float* __restrict__ Wk, const float* __restrict__ Wq,
    const float* __restrict__ Wv, unsigned short* __restrict__ Wt)
{
    __shared__ float ws[64][65];
    const int m = blockIdx.x >> 4, kc = blockIdx.x & 15;
    const float* W = (m == 0) ? Wq : (m == 1) ? Wk : Wv;
    const float scale = (m == 0) ? 0.18033688011112042f : 1.0f;
    const int tid = threadIdx.x;
    #pragma unroll
    for (int r = 0; r < 16; ++r) {
        int idx = r * 256 + tid;
        ws[idx >> 6][idx & 63] = W[(kc * 64 + (idx >> 6)) * 64 + (idx & 63)] * scale;
    }
    __syncthreads();
    const int c = tid >> 2, k4 = (tid & 3) * 16;
    bf16x8 o0, o1;
    #pragma unroll
    for (int j = 0; j < 8; ++j) o0[j] = (short)f2bf(ws[k4 + j][c]);
    #pragma unroll
    for (int j = 0; j < 8; ++j) o1[j] = (short)f2bf(ws[k4 + 8 + j][c]);
    unsigned short* dst = Wt + ((size_t)m * 64 + c) * 1024 + kc * 64 + k4;
    *(bf16x8*)dst = o0;
    *(bf16x8*)(dst + 8) = o1;
}

// ---------------------------------------------------------------------------
// Kernel 1: proj split-K=2. Wave = 16 rows x 512 K-half. f32 partials.
// ---------------------------------------------------------------------------
__global__ __launch_bounds__(256) void proj_kernel(
    const float* __restrict__ x, const unsigned short* __restrict__ Wt,
    float* __restrict__ pq, float* __restrict__ pk, float* __restrict__ pv)
{
    const int tid = threadIdx.x;
    const int gw = blockIdx.x * 4 + (tid >> 6);   // 0..2047
    const int l = tid & 63;
    const int xr = l & 15, g = l >> 4;
    const int half = gw & 1;
    const int row0 = (gw >> 1) * 16;

    const float* xp = x + (size_t)(row0 + xr) * 1024 + half * 512 + 8 * g;

    const unsigned short* wb[3][4];
    #pragma unroll
    for (int m = 0; m < 3; ++m)
        #pragma unroll
        for (int t = 0; t < 4; ++t)
            wb[m][t] = Wt + ((size_t)(m * 64 + 16 * t + xr)) * 1024 + half * 512 + 8 * g;

    f32x4 acc[3][4];
    #pragma unroll
    for (int m = 0; m < 3; ++m)
        #pragma unroll
        for (int t = 0; t < 4; ++t) { f32x4 z = {0.f,0.f,0.f,0.f}; acc[m][t] = z; }

    float4 xa = *(const float4*)xp;
    float4 xb = *(const float4*)(xp + 4);
    #pragma unroll
    for (int s = 0; s < 16; ++s) {
        float4 xan = xa, xbn = xb;
        if (s < 15) {
            xan = *(const float4*)(xp + 32 * (s + 1));
            xbn = *(const float4*)(xp + 32 * (s + 1) + 4);
        }
        bf16x8 a;
        a[0] = (short)f2bf(xa.x); a[1] = (short)f2bf(xa.y);
        a[2] = (short)f2bf(xa.z); a[3] = (short)f2bf(xa.w);
        a[4] = (short)f2bf(xb.x); a[5] = (short)f2bf(xb.y);
        a[6] = (short)f2bf(xb.z); a[7] = (short)f2bf(xb.w);
        #pragma unroll
        for (int m = 0; m < 3; ++m)
            #pragma unroll
            for (int t = 0; t < 4; ++t) {
                bf16x8 bfr = *(const bf16x8*)(wb[m][t] + 32 * s);
                acc[m][t] = __builtin_amdgcn_mfma_f32_16x16x32_bf16(a, bfr, acc[m][t], 0, 0, 0);
            }
        xa = xan; xb = xbn;
    }

    const size_t hoff = (size_t)half * 16384 * 64;
    #pragma unroll
    for (int t = 0; t < 4; ++t)
        #pragma unroll
        for (int i = 0; i < 4; ++i) {
            const size_t row = row0 + 4 * g + i;
            const int col = xr + 16 * t;
            pq[hoff + row * 64 + col] = acc[0][t][i];
            pk[hoff + row * 64 + col] = acc[1][t][i];
            pv[hoff + row * 64 + col] = acc[2][t][i];
        }
}

// ---------------------------------------------------------------------------
// Kernel 2: combine halves -> bf16 qw/kw (row-major), vT (transposed [b][d][key])
// ---------------------------------------------------------------------------
__global__ __launch_bounds__(256) void reduce_kernel(
    const float* __restrict__ pq, const float* __restrict__ pk,
    const float* __restrict__ pv,
    unsigned short* __restrict__ qw, unsigned short* __restrict__ kw,
    unsigned short* __restrict__ vT)
{
    const int gid = blockIdx.x * 256 + threadIdx.x;   // 0..49151
    if (gid < 32768) {
        const int mat = gid >> 14;
        const int row = gid & 16383;
        const float* s0 = (mat ? pk : pq) + (size_t)row * 64;
        const float* s1 = s0 + (size_t)16384 * 64;
        unsigned short* dst = (mat ? kw : qw) + (size_t)row * 64;
        #pragma unroll
        for (int c = 0; c < 8; ++c) {
            float4 a0 = *(const float4*)(s0 + 8 * c);
            float4 a1 = *(const float4*)(s0 + 8 * c + 4);
            float4 b0 = *(const float4*)(s1 + 8 * c);
            float4 b1 = *(const float4*)(s1 + 8 * c + 4);
            bf16x8 o;
            o[0] = (short)f2bf(a0.x + b0.x); o[1] = (short)f2bf(a0.y + b0.y);
            o[2] = (short)f2bf(a0.z + b0.z); o[3] = (short)f2bf(a0.w + b0.w);
            o[4] = (short)f2bf(a1.x + b1.x); o[5] = (short)f2bf(a1.y + b1.y);
            o[6] = (short)f2bf(a1.z + b1.z); o[7] = (short)f2bf(a1.w + b1.w);
            *(bf16x8*)(dst + 8 * c) = o;
        }
    } else {
        const int t2 = gid - 32768;                   // 0..16383
        const int b = t2 >> 12, kb = (t2 >> 6) & 63, d = t2 & 63;
        const float* s0 = pv + ((size_t)(b * 4096 + kb * 64)) * 64 + d;
        const float* s1 = s0 + (size_t)16384 * 64;
        unsigned short* dst = vT + (size_t)(b * 64 + d) * 4096 + kb * 64;
        #pragma unroll
        for (int c8 = 0; c8 < 8; ++c8) {
            bf16x8 o;
            #pragma unroll
            for (int j = 0; j < 8; ++j) {
                const int r = c8 * 8 + j;
                o[j] = (short)f2bf(s0[(size_t)r * 64] + s1[(size_t)r * 64]);
            }
            *(bf16x8*)(dst + 8 * c8) = o;
        }
    }
}

// ---------------------------------------------------------------------------
// Kernel 3: split-K flash attention. WG = (batch, 64-row q-block, 1024-key chunk).
// 4 waves x 16 rows. K/V double-buffered in LDS via global_load_lds.
// Writes unnormalized O, m, l partials.
// ---------------------------------------------------------------------------
__global__ __launch_bounds__(256) void attn_kernel(
    const unsigned short* __restrict__ qw, const unsigned short* __restrict__ kw,
    const unsigned short* __restrict__ vT,
    float* __restrict__ PO, float* __restrict__ Pm, float* __restrict__ Pl)
{
    __shared__ unsigned short Kb[2][4096];   // 8KB per buf, [key][d]
    __shared__ unsigned short Vb[2][4096];   // 8KB per buf, [d][key]
    __shared__ unsigned short Ps[4][16][72];

    const int tid = threadIdx.x;
    const int w = tid >> 6, l = tid & 63;
    const int xr = l & 15, g = l >> 4;

    const int bidx = blockIdx.x;             // 0..639
    const int b = bidx / 160;
    const int idx = bidx - b * 160;
    int qb, c;
    if (idx < 16)      { qb = idx;                  c = 0; }
    else if (idx < 48) { qb = 16 + ((idx - 16) >> 1); c = (idx - 16) & 1; }
    else if (idx < 96) { qb = 32 + (idx - 48) / 3;  c = (idx - 48) % 3; }
    else               { qb = 48 + ((idx - 96) >> 2); c = (idx - 96) & 3; }

    const int t0 = c * 16;
    const int tcnt_ = qb + 1 - t0;
    const int tcnt = tcnt_ < 16 ? tcnt_ : 16;
    const size_t base = (size_t)b * 4096;
    const int qrow = qb * 64 + w * 16;       // local row within batch

    bf16x8 aq[2];
    #pragma unroll
    for (int h = 0; h < 2; ++h)
        aq[h] = *(const bf16x8*)(qw + (base + qrow + xr) * 64 + 32 * h + 8 * g);

    const int wo0 = (w * 2 + 0) * 1024;      // wave-uniform byte offsets in 8KB tile
    const int wo1 = (w * 2 + 1) * 1024;
    const char* kwb = (const char*)kw + base * 128;
    const char* vtb0 = (const char*)vT + (size_t)b * 64 * 8192;

    auto stage = [&](int bi, int it) {
        const char* kt = kwb + (size_t)it * 8192;
        gl_lds16(kt + wo0 + l * 16, (char*)Kb[bi] + wo0);
        gl_lds16(kt + wo1 + l * 16, (char*)Kb[bi] + wo1);
        const char* vtb = vtb0 + (size_t)it * 128;
        int o0 = wo0 + l * 16;
        gl_lds16(vtb + (size_t)(o0 >> 7) * 8192 + (o0 & 127), (char*)Vb[bi] + wo0);
        int o1 = wo1 + l * 16;
        gl_lds16(vtb + (size_t)(o1 >> 7) * 8192 + (o1 & 127), (char*)Vb[bi] + wo1);
    };

    f32x4 accO[4];
    #pragma unroll
    for (int t = 0; t < 4; ++t) { f32x4 z = {0.f,0.f,0.f,0.f}; accO[t] = z; }
    f32x4 mrow = {-1e30f, -1e30f, -1e30f, -1e30f};
    f32x4 lsum = {0.f, 0.f, 0.f, 0.f};

    stage(0, t0);
    __syncthreads();

    for (int tt = 0; tt < tcnt; ++tt) {
        const int it = t0 + tt;
        const int bi = tt & 1;
        if (tt + 1 < tcnt) stage(bi ^ 1, it + 1);

        // S = Q K^T
        f32x4 s[4];
        #pragma unroll
        for (int t = 0; t < 4; ++t) {
            f32x4 z = {0.f,0.f,0.f,0.f};
            s[t] = z;
            #pragma unroll
            for (int h = 0; h < 2; ++h) {
                bf16x8 bk = *(const bf16x8*)&Kb[bi][(xr + 16 * t) * 64 + 32 * h + 8 * g];
                s[t] = __builtin_amdgcn_mfma_f32_16x16x32_bf16(aq[h], bk, s[t], 0, 0, 0);
            }
        }

        if (it == qb) {   // diagonal tile: causal mask
            #pragma unroll
            for (int t = 0; t < 4; ++t)
                #pragma unroll
                for (int i = 0; i < 4; ++i) {
                    int key = it * 64 + xr + 16 * t;
                    int row = qrow + 4 * g + i;
                    if (key > row) s[t][i] = -1e30f;
                }
        }

        f32x4 tmax = s[0];
        #pragma unroll
        for (int t = 1; t < 4; ++t)
            #pragma unroll
            for (int i = 0; i < 4; ++i) tmax[i] = fmaxf(tmax[i], s[t][i]);
        #pragma unroll
        for (int off = 1; off < 16; off <<= 1)
            #pragma unroll
            for (int i = 0; i < 4; ++i)
                tmax[i] = fmaxf(tmax[i], __shfl_xor(tmax[i], off, 64));

        f32x4 mnew, fac;
        #pragma unroll
        for (int i = 0; i < 4; ++i) {
            mnew[i] = fmaxf(mrow[i], tmax[i]);
            fac[i]  = exp2f(mrow[i] - mnew[i]);
        }

        f32x4 psum = {0.f, 0.f, 0.f, 0.f};
        #pragma unroll
        for (int t = 0; t < 4; ++t)
            #pragma unroll
            for (int i = 0; i < 4; ++i) {
                float p = exp2f(s[t][i] - mnew[i]);
                psum[i] += p;
                Ps[w][4 * g + i][xr + 16 * t] = f2bf(p);
            }
        #pragma unroll
        for (int off = 1; off < 16; off <<= 1)
            #pragma unroll
            for (int i = 0; i < 4; ++i)
                psum[i] += __shfl_xor(psum[i], off, 64);

        #pragma unroll
        for (int i = 0; i < 4; ++i) {
            lsum[i] = lsum[i] * fac[i] + psum[i];
            mrow[i] = mnew[i];
        }
        #pragma unroll
        for (int t = 0; t < 4; ++t)
            #pragma unroll
            for (int i = 0; i < 4; ++i) accO[t][i] *= fac[i];

        #pragma unroll
        for (int h = 0; h < 2; ++h) {
            bf16x8 pa = *(const bf16x8*)&Ps[w][xr][32 * h + 8 * g];
            #pragma unroll
            for (int t = 0; t < 4; ++t) {
                bf16x8 bv = *(const bf16x8*)&Vb[bi][(xr + 16 * t) * 64 + 32 * h + 8 * g];
                accO[t] = __builtin_amdgcn_mfma_f32_16x16x32_bf16(pa, bv, accO[t], 0, 0, 0);
            }
        }

        __syncthreads();   // next buf staged + all waves done with this buf
    }

    const size_t prow = (size_t)(b * 4 + c) * 4096 + qrow;
    #pragma unroll
    for (int t = 0; t < 4; ++t)
        #pragma unroll
        for (int i = 0; i < 4; ++i)
            PO[(prow + 4 * g + i) * 64 + xr + 16 * t] = accO[t][i];
    if (xr == 0) {
        #pragma unroll
        for (int i = 0; i < 4; ++i) {
            Pm[prow + 4 * g + i] = mrow[i];
            Pl[prow + 4 * g + i] = lsum[i];
        }
    }
}

// ---------------------------------------------------------------------------
// Kernel 4: merge <=4 chunk partials per row -> out
// ---------------------------------------------------------------------------
__global__ __launch_bounds__(256) void merge_kernel(
    const float* __restrict__ PO, const float* __restrict__ Pm,
    const float* __restrict__ Pl, float* __restrict__ out)
{
    const int gid = blockIdx.x * 256 + threadIdx.x;  // 0..65535
    const int r = gid >> 2;
    const int c0 = (gid & 3) * 16;
    const int b = r >> 12, lr = r & 4095;
    const int nc = (lr >> 10) + 1;

    float mv[4], lv[4];
    #pragma unroll
    for (int ci = 0; ci < 4; ++ci) {
        mv[ci] = (ci < nc) ? Pm[(size_t)(b * 4 + ci) * 4096 + lr] : -1e30f;
        lv[ci] = (ci < nc) ? Pl[(size_t)(b * 4 + ci) * 4096 + lr] : 0.f;
    }
    float M = fmaxf(fmaxf(mv[0], mv[1]), fmaxf(mv[2], mv[3]));
    float wgt[4];
    float L = 0.f;
    #pragma unroll
    for (int ci = 0; ci < 4; ++ci) {
        wgt[ci] = exp2f(mv[ci] - M);
        L += wgt[ci] * lv[ci];
    }
    const float rL = 1.0f / L;

    f32x4 acc[4];
    #pragma unroll
    for (int j = 0; j < 4; ++j) { f32x4 z = {0.f,0.f,0.f,0.f}; acc[j] = z; }
    #pragma unroll
    for (int ci = 0; ci < 4; ++ci) {
        if (ci < nc) {
            const float* p = PO + ((size_t)(b * 4 + ci) * 4096 + lr) * 64 + c0;
            #pragma unroll
            for (int j = 0; j < 4; ++j) {
                float4 v = *(const float4*)(p + 4 * j);
                acc[j][0] += wgt[ci] * v.x; acc[j][1] += wgt[ci] * v.y;
                acc[j][2] += wgt[ci] * v.z; acc[j][3] += wgt[ci] * v.w;
            }
        }
    }
    float* op = out + (size_t)r * 64 + c0;
    #pragma unroll
    for (int j = 0; j < 4; ++j) {
        float4 v;
        v.x = acc[j][0] * rL; v.y = acc[j][1] * rL;
        v.z = acc[j][2] * rL; v.w = acc[j][3] * rL;
        *(float4*)(op + 4 * j) = v;
    }
}

extern "C" void kernel_launch(void* const* d_in, const int* in_sizes, int n_in,
                              void* d_out, int out_size, void* d_ws, size_t ws_size,
                              hipStream_t stream) {
    const float* x  = (const float*)d_in[0];
    const float* Wk = (const float*)d_in[1];
    const float* Wq = (const float*)d_in[2];
    const float* Wv = (const float*)d_in[3];
    float* out = (float*)d_out;

    char* wsb = (char*)d_ws;
    // proj-phase scratch (24MB), later overlaid by attention partials
    float* pq = (float*)wsb;                         // [2][16384][64]
    float* pk = pq + (size_t)2 * 16384 * 64;         // [2][16384][64]
    float* pv = pk + (size_t)2 * 16384 * 64;         // [2][16384][64]
    float* PO = (float*)wsb;                         // [16][4096][64] overlay
    float* Pm = PO + (size_t)16 * 4096 * 64;         // [16][4096]
    float* Pl = Pm + (size_t)16 * 4096;
    // persistent bf16 region above 24MB
    unsigned short* Wt = (unsigned short*)(wsb + (size_t)24 * 1024 * 1024);
    unsigned short* qw = Wt + (size_t)3 * 64 * 1024; // [16384][64]
    unsigned short* kw = qw + (size_t)16384 * 64;    // [16384][64]
    unsigned short* vT = kw + (size_t)16384 * 64;    // [4][64][4096]

    hipLaunchKernelGGL(wt_kernel, dim3(48), dim3(256), 0, stream, Wk, Wq, Wv, Wt);
    hipLaunchKernelGGL(proj_kernel, dim3(512), dim3(256), 0, stream, x, Wt, pq, pk, pv);
    hipLaunchKernelGGL(reduce_kernel, dim3(192), dim3(256), 0, stream, pq, pk, pv, qw, kw, vT);
    hipLaunchKernelGGL(attn_kernel, dim3(640), dim3(256), 0, stream, qw, kw, vT, PO, Pm, Pl);
    hipLaunchKernelGGL(merge_kernel, dim3(256), dim3(256), 0, stream, PO, Pm, Pl, out);
}

// Round 4
// 100.648 us; speedup vs baseline: 3.6253x; 1.4601x over previous
//
#include <hip/hip_runtime.h>

typedef __attribute__((ext_vector_type(8))) short bf16x8;
typedef __attribute__((ext_vector_type(4))) float f32x4;

#define DI __device__ __forceinline__

DI unsigned short f2bf(float f) {
    unsigned int u = __builtin_bit_cast(unsigned int, f);
    u += 0x7fff + ((u >> 16) & 1);
    return (unsigned short)(u >> 16);
}

DI void gl_lds16(const void* g, void* l) {
    __builtin_amdgcn_global_load_lds(
        (const __attribute__((address_space(1))) unsigned int*)g,
        (__attribute__((address_space(3))) unsigned int*)l, 16, 0, 0);
}

// ---------------------------------------------------------------------------
// Kernel 0: Wt[m][c][k] = W_m[k][c] * scale_m (bf16). m: 0=q(scaled),1=k,2=v
// scale_q = 0.125 * log2(e) -> softmax in exp2 domain downstream.
// ---------------------------------------------------------------------------
__global__ __launch_bounds__(256) void wt_kernel(
    const float* __restrict__ Wk, const float* __restrict__ Wq,
    const float* __restrict__ Wv, unsigned short* __restrict__ Wt)
{
    __shared__ float ws[64][65];
    const int m = blockIdx.x >> 4, kc = blockIdx.x & 15;
    const float* W = (m == 0) ? Wq : (m == 1) ? Wk : Wv;
    const float scale = (m == 0) ? 0.18033688011112042f : 1.0f;
    const int tid = threadIdx.x;
    #pragma unroll
    for (int r = 0; r < 16; ++r) {
        int idx = r * 256 + tid;
        ws[idx >> 6][idx & 63] = W[(kc * 64 + (idx >> 6)) * 64 + (idx & 63)] * scale;
    }
    __syncthreads();
    const int c = tid >> 2, k4 = (tid & 3) * 16;
    bf16x8 o0, o1;
    #pragma unroll
    for (int j = 0; j < 8; ++j) o0[j] = (short)f2bf(ws[k4 + j][c]);
    #pragma unroll
    for (int j = 0; j < 8; ++j) o1[j] = (short)f2bf(ws[k4 + 8 + j][c]);
    unsigned short* dst = Wt + ((size_t)m * 64 + c) * 1024 + kc * 64 + k4;
    *(bf16x8*)dst = o0;
    *(bf16x8*)(dst + 8) = o1;
}

// ---------------------------------------------------------------------------
// Kernel 1: proj, m97-style. Block = 64 rows x 32-col half of all 3 mats.
// grid 512: rb = blockIdx&255 (row block), ch = blockIdx>>8 (col half -> same
// XCD as its sibling so x is L2-shared). BK=32, dbuf LDS via global_load_lds,
// XOR-swizzled (pre-swizzled global src + swizzled ds_read), 1 barrier/step.
// ---------------------------------------------------------------------------
__global__ __launch_bounds__(256) void proj_kernel(
    const float* __restrict__ x, const unsigned short* __restrict__ Wt,
    unsigned short* __restrict__ qw, unsigned short* __restrict__ kw,
    unsigned short* __restrict__ vT)
{
    __shared__ char LDSx[2][8192];   // x tile [64 rows][32 f32], swizzled
    __shared__ char LDSb[2][6144];   // B tile [96 rows][32 bf16], swizzled

    const int tid = threadIdx.x;
    const int w = tid >> 6, l = tid & 63;
    const int xr = l & 15, lg = l >> 4;
    const int rb = blockIdx.x & 255, ch = blockIdx.x >> 8;
    const int row0 = rb * 64;

    const char* xsrc = (const char*)x + (size_t)row0 * 4096;
    const char* Wtb = (const char*)Wt;

    // per-lane staging coordinates (chunk-invariant parts)
    const int xrow_l = l >> 3, xcb = (l & 7) * 16;          // x: row offset within chunk, col byte
    const int brow_l = l >> 2, bcb = (l & 3) * 16;          // B

    auto stage = [&](int nb, int s) {
        #pragma unroll
        for (int c = 0; c < 4; ++c) {
            const int ci = w + 4 * c;
            if (ci < 8) {
                const int row = ci * 8 + xrow_l;
                const int sw = (row & 7) << 4;
                gl_lds16(xsrc + (size_t)row * 4096 + (size_t)s * 128 + (xcb ^ sw),
                         LDSx[nb] + ci * 1024);
            } else if (ci < 14) {
                const int c8 = ci - 8;
                const int r = c8 * 16 + brow_l;
                const int sw = ((r >> 1) & 3) << 4;
                const int wtrow = (r >> 5) * 64 + ch * 32 + (r & 31);
                gl_lds16(Wtb + (size_t)wtrow * 2048 + (size_t)s * 64 + (bcb ^ sw),
                         LDSb[nb] + c8 * 1024);
            }
        }
    };

    f32x4 acc[3][2];
    #pragma unroll
    for (int m = 0; m < 3; ++m)
        #pragma unroll
        for (int tt = 0; tt < 2; ++tt) { f32x4 z = {0.f,0.f,0.f,0.f}; acc[m][tt] = z; }

    stage(0, 0);
    __syncthreads();

    const int Rw = w * 16 + xr;
    const int swx = (Rw & 7) << 4;

    for (int s = 0; s < 32; ++s) {
        const int pb = s & 1;
        if (s < 31) stage(pb ^ 1, s + 1);

        // A: 8 f32 -> bf16
        float4 va = *(const float4*)(LDSx[pb] + Rw * 128 + ((32 * lg) ^ swx));
        float4 vb = *(const float4*)(LDSx[pb] + Rw * 128 + ((32 * lg + 16) ^ swx));
        bf16x8 a;
        a[0] = (short)f2bf(va.x); a[1] = (short)f2bf(va.y);
        a[2] = (short)f2bf(va.z); a[3] = (short)f2bf(va.w);
        a[4] = (short)f2bf(vb.x); a[5] = (short)f2bf(vb.y);
        a[6] = (short)f2bf(vb.z); a[7] = (short)f2bf(vb.w);

        #pragma unroll
        for (int m = 0; m < 3; ++m)
            #pragma unroll
            for (int tt = 0; tt < 2; ++tt) {
                const int rB = m * 32 + tt * 16 + xr;
                bf16x8 bfr = *(const bf16x8*)(LDSb[pb] + rB * 64 +
                                ((16 * lg) ^ (((rB >> 1) & 3) << 4)));
                acc[m][tt] = __builtin_amdgcn_mfma_f32_16x16x32_bf16(a, bfr, acc[m][tt], 0, 0, 0);
            }
        __syncthreads();
    }

    // epilogue: D layout col = l&15 (+16tt+32ch), row = lg*4 + i
    const int bb = row0 >> 12;
    #pragma unroll
    for (int tt = 0; tt < 2; ++tt) {
        const int col = ch * 32 + tt * 16 + xr;
        unsigned short pv4[4];
        #pragma unroll
        for (int i = 0; i < 4; ++i) {
            const int grow = row0 + w * 16 + 4 * lg + i;
            qw[(size_t)grow * 64 + col] = f2bf(acc[0][tt][i]);
            kw[(size_t)grow * 64 + col] = f2bf(acc[1][tt][i]);
            pv4[i] = f2bf(acc[2][tt][i]);
        }
        const int lr0 = (row0 & 4095) + w * 16 + 4 * lg;
        *(uint2*)&vT[((size_t)bb * 64 + col) * 4096 + lr0] = *(const uint2*)pv4;
    }
}

// ---------------------------------------------------------------------------
// Kernel 3: split-K flash attention (unchanged from R3).
// ---------------------------------------------------------------------------
__global__ __launch_bounds__(256) void attn_kernel(
    const unsigned short* __restrict__ qw, const unsigned short* __restrict__ kw,
    const unsigned short* __restrict__ vT,
    float* __restrict__ PO, float* __restrict__ Pm, float* __restrict__ Pl)
{
    __shared__ unsigned short Kb[2][4096];
    __shared__ unsigned short Vb[2][4096];
    __shared__ unsigned short Ps[4][16][72];

    const int tid = threadIdx.x;
    const int w = tid >> 6, l = tid & 63;
    const int xr = l & 15, g = l >> 4;

    const int bidx = blockIdx.x;
    const int b = bidx / 160;
    const int idx = bidx - b * 160;
    int qb, c;
    if (idx < 16)      { qb = idx;                  c = 0; }
    else if (idx < 48) { qb = 16 + ((idx - 16) >> 1); c = (idx - 16) & 1; }
    else if (idx < 96) { qb = 32 + (idx - 48) / 3;  c = (idx - 48) % 3; }
    else               { qb = 48 + ((idx - 96) >> 2); c = (idx - 96) & 3; }

    const int t0 = c * 16;
    const int tcnt_ = qb + 1 - t0;
    const int tcnt = tcnt_ < 16 ? tcnt_ : 16;
    const size_t base = (size_t)b * 4096;
    const int qrow = qb * 64 + w * 16;

    bf16x8 aq[2];
    #pragma unroll
    for (int h = 0; h < 2; ++h)
        aq[h] = *(const bf16x8*)(qw + (base + qrow + xr) * 64 + 32 * h + 8 * g);

    const int wo0 = (w * 2 + 0) * 1024;
    const int wo1 = (w * 2 + 1) * 1024;
    const char* kwb = (const char*)kw + base * 128;
    const char* vtb0 = (const char*)vT + (size_t)b * 64 * 8192;

    auto stage = [&](int bi, int it) {
        const char* kt = kwb + (size_t)it * 8192;
        gl_lds16(kt + wo0 + l * 16, (char*)Kb[bi] + wo0);
        gl_lds16(kt + wo1 + l * 16, (char*)Kb[bi] + wo1);
        const char* vtb = vtb0 + (size_t)it * 128;
        int o0 = wo0 + l * 16;
        gl_lds16(vtb + (size_t)(o0 >> 7) * 8192 + (o0 & 127), (char*)Vb[bi] + wo0);
        int o1 = wo1 + l * 16;
        gl_lds16(vtb + (size_t)(o1 >> 7) * 8192 + (o1 & 127), (char*)Vb[bi] + wo1);
    };

    f32x4 accO[4];
    #pragma unroll
    for (int t = 0; t < 4; ++t) { f32x4 z = {0.f,0.f,0.f,0.f}; accO[t] = z; }
    f32x4 mrow = {-1e30f, -1e30f, -1e30f, -1e30f};
    f32x4 lsum = {0.f, 0.f, 0.f, 0.f};

    stage(0, t0);
    __syncthreads();

    for (int tt = 0; tt < tcnt; ++tt) {
        const int it = t0 + tt;
        const int bi = tt & 1;
        if (tt + 1 < tcnt) stage(bi ^ 1, it + 1);

        f32x4 s[4];
        #pragma unroll
        for (int t = 0; t < 4; ++t) {
            f32x4 z = {0.f,0.f,0.f,0.f};
            s[t] = z;
            #pragma unroll
            for (int h = 0; h < 2; ++h) {
                bf16x8 bk = *(const bf16x8*)&Kb[bi][(xr + 16 * t) * 64 + 32 * h + 8 * g];
                s[t] = __builtin_amdgcn_mfma_f32_16x16x32_bf16(aq[h], bk, s[t], 0, 0, 0);
            }
        }

        if (it == qb) {
            #pragma unroll
            for (int t = 0; t < 4; ++t)
                #pragma unroll
                for (int i = 0; i < 4; ++i) {
                    int key = it * 64 + xr + 16 * t;
                    int row = qrow + 4 * g + i;
                    if (key > row) s[t][i] = -1e30f;
                }
        }

        f32x4 tmax = s[0];
        #pragma unroll
        for (int t = 1; t < 4; ++t)
            #pragma unroll
            for (int i = 0; i < 4; ++i) tmax[i] = fmaxf(tmax[i], s[t][i]);
        #pragma unroll
        for (int off = 1; off < 16; off <<= 1)
            #pragma unroll
            for (int i = 0; i < 4; ++i)
                tmax[i] = fmaxf(tmax[i], __shfl_xor(tmax[i], off, 64));

        f32x4 mnew, fac;
        #pragma unroll
        for (int i = 0; i < 4; ++i) {
            mnew[i] = fmaxf(mrow[i], tmax[i]);
            fac[i]  = exp2f(mrow[i] - mnew[i]);
        }

        f32x4 psum = {0.f, 0.f, 0.f, 0.f};
        #pragma unroll
        for (int t = 0; t < 4; ++t)
            #pragma unroll
            for (int i = 0; i < 4; ++i) {
                float p = exp2f(s[t][i] - mnew[i]);
                psum[i] += p;
                Ps[w][4 * g + i][xr + 16 * t] = f2bf(p);
            }
        #pragma unroll
        for (int off = 1; off < 16; off <<= 1)
            #pragma unroll
            for (int i = 0; i < 4; ++i)
                psum[i] += __shfl_xor(psum[i], off, 64);

        #pragma unroll
        for (int i = 0; i < 4; ++i) {
            lsum[i] = lsum[i] * fac[i] + psum[i];
            mrow[i] = mnew[i];
        }
        #pragma unroll
        for (int t = 0; t < 4; ++t)
            #pragma unroll
            for (int i = 0; i < 4; ++i) accO[t][i] *= fac[i];

        #pragma unroll
        for (int h = 0; h < 2; ++h) {
            bf16x8 pa = *(const bf16x8*)&Ps[w][xr][32 * h + 8 * g];
            #pragma unroll
            for (int t = 0; t < 4; ++t) {
                bf16x8 bv = *(const bf16x8*)&Vb[bi][(xr + 16 * t) * 64 + 32 * h + 8 * g];
                accO[t] = __builtin_amdgcn_mfma_f32_16x16x32_bf16(pa, bv, accO[t], 0, 0, 0);
            }
        }

        __syncthreads();
    }

    const size_t prow = (size_t)(b * 4 + c) * 4096 + qrow;
    #pragma unroll
    for (int t = 0; t < 4; ++t)
        #pragma unroll
        for (int i = 0; i < 4; ++i)
            PO[(prow + 4 * g + i) * 64 + xr + 16 * t] = accO[t][i];
    if (xr == 0) {
        #pragma unroll
        for (int i = 0; i < 4; ++i) {
            Pm[prow + 4 * g + i] = mrow[i];
            Pl[prow + 4 * g + i] = lsum[i];
        }
    }
}

// ---------------------------------------------------------------------------
// Kernel 4: merge <=4 chunk partials per row -> out (unchanged).
// ---------------------------------------------------------------------------
__global__ __launch_bounds__(256) void merge_kernel(
    const float* __restrict__ PO, const float* __restrict__ Pm,
    const float* __restrict__ Pl, float* __restrict__ out)
{
    const int gid = blockIdx.x * 256 + threadIdx.x;
    const int r = gid >> 2;
    const int c0 = (gid & 3) * 16;
    const int b = r >> 12, lr = r & 4095;
    const int nc = (lr >> 10) + 1;

    float mv[4], lv[4];
    #pragma unroll
    for (int ci = 0; ci < 4; ++ci) {
        mv[ci] = (ci < nc) ? Pm[(size_t)(b * 4 + ci) * 4096 + lr] : -1e30f;
        lv[ci] = (ci < nc) ? Pl[(size_t)(b * 4 + ci) * 4096 + lr] : 0.f;
    }
    float M = fmaxf(fmaxf(mv[0], mv[1]), fmaxf(mv[2], mv[3]));
    float wgt[4];
    float L = 0.f;
    #pragma unroll
    for (int ci = 0; ci < 4; ++ci) {
        wgt[ci] = exp2f(mv[ci] - M);
        L += wgt[ci] * lv[ci];
    }
    const float rL = 1.0f / L;

    f32x4 acc[4];
    #pragma unroll
    for (int j = 0; j < 4; ++j) { f32x4 z = {0.f,0.f,0.f,0.f}; acc[j] = z; }
    #pragma unroll
    for (int ci = 0; ci < 4; ++ci) {
        if (ci < nc) {
            const float* p = PO + ((size_t)(b * 4 + ci) * 4096 + lr) * 64 + c0;
            #pragma unroll
            for (int j = 0; j < 4; ++j) {
                float4 v = *(const float4*)(p + 4 * j);
                acc[j][0] += wgt[ci] * v.x; acc[j][1] += wgt[ci] * v.y;
                acc[j][2] += wgt[ci] * v.z; acc[j][3] += wgt[ci] * v.w;
            }
        }
    }
    float* op = out + (size_t)r * 64 + c0;
    #pragma unroll
    for (int j = 0; j < 4; ++j) {
        float4 v;
        v.x = acc[j][0] * rL; v.y = acc[j][1] * rL;
        v.z = acc[j][2] * rL; v.w = acc[j][3] * rL;
        *(float4*)(op + 4 * j) = v;
    }
}

extern "C" void kernel_launch(void* const* d_in, const int* in_sizes, int n_in,
                              void* d_out, int out_size, void* d_ws, size_t ws_size,
                              hipStream_t stream) {
    const float* x  = (const float*)d_in[0];
    const float* Wk = (const float*)d_in[1];
    const float* Wq = (const float*)d_in[2];
    const float* Wv = (const float*)d_in[3];
    float* out = (float*)d_out;

    char* wsb = (char*)d_ws;
    float* PO = (float*)wsb;                         // [16][4096][64]
    float* Pm = PO + (size_t)16 * 4096 * 64;         // [16][4096]
    float* Pl = Pm + (size_t)16 * 4096;
    unsigned short* Wt = (unsigned short*)(wsb + (size_t)24 * 1024 * 1024);
    unsigned short* qw = Wt + (size_t)3 * 64 * 1024; // [16384][64]
    unsigned short* kw = qw + (size_t)16384 * 64;    // [16384][64]
    unsigned short* vT = kw + (size_t)16384 * 64;    // [4][64][4096]

    hipLaunchKernelGGL(wt_kernel, dim3(48), dim3(256), 0, stream, Wk, Wq, Wv, Wt);
    hipLaunchKernelGGL(proj_kernel, dim3(512), dim3(256), 0, stream, x, Wt, qw, kw, vT);
    hipLaunchKernelGGL(attn_kernel, dim3(640), dim3(256), 0, stream, qw, kw, vT, PO, Pm, Pl);
    hipLaunchKernelGGL(merge_kernel, dim3(256), dim3(256), 0, stream, PO, Pm, Pl, out);
}

// Round 5
// 79.646 us; speedup vs baseline: 4.5813x; 1.2637x over previous
//
#include <hip/hip_runtime.h>

typedef __attribute__((ext_vector_type(8))) short bf16x8;
typedef __attribute__((ext_vector_type(4))) float f32x4;

#define DI __device__ __forceinline__

DI unsigned short f2bf(float f) {
    unsigned int u = __builtin_bit_cast(unsigned int, f);
    u += 0x7fff + ((u >> 16) & 1);
    return (unsigned short)(u >> 16);
}

DI unsigned int cvtpk(float lo, float hi) {
    unsigned int r;
    asm("v_cvt_pk_bf16_f32 %0, %1, %2" : "=v"(r) : "v"(lo), "v"(hi));
    return r;
}

DI void gl_lds16(const void* g, void* l) {
    __builtin_amdgcn_global_load_lds(
        (const __attribute__((address_space(1))) unsigned int*)g,
        (__attribute__((address_space(3))) unsigned int*)l, 16, 0, 0);
}

// ---------------------------------------------------------------------------
// Kernel 0: Wt[m][c][k] = W_m[k][c] * scale_m (bf16). m: 0=q(scaled),1=k,2=v
// scale_q = 0.125 * log2(e) -> softmax in exp2 domain downstream.
// ---------------------------------------------------------------------------
__global__ __launch_bounds__(256) void wt_kernel(
    const float* __restrict__ Wk, const float* __restrict__ Wq,
    const float* __restrict__ Wv, unsigned short* __restrict__ Wt)
{
    __shared__ float ws[64][65];
    const int m = blockIdx.x >> 4, kc = blockIdx.x & 15;
    const float* W = (m == 0) ? Wq : (m == 1) ? Wk : Wv;
    const float scale = (m == 0) ? 0.18033688011112042f : 1.0f;
    const int tid = threadIdx.x;
    #pragma unroll
    for (int r = 0; r < 16; ++r) {
        int idx = r * 256 + tid;
        ws[idx >> 6][idx & 63] = W[(kc * 64 + (idx >> 6)) * 64 + (idx & 63)] * scale;
    }
    __syncthreads();
    const int c = tid >> 2, k4 = (tid & 3) * 16;
    bf16x8 o0, o1;
    #pragma unroll
    for (int j = 0; j < 8; ++j) o0[j] = (short)f2bf(ws[k4 + j][c]);
    #pragma unroll
    for (int j = 0; j < 8; ++j) o1[j] = (short)f2bf(ws[k4 + 8 + j][c]);
    unsigned short* dst = Wt + ((size_t)m * 64 + c) * 1024 + kc * 64 + k4;
    *(bf16x8*)dst = o0;
    *(bf16x8*)(dst + 8) = o1;
}

// ---------------------------------------------------------------------------
// Kernel 1: proj (unchanged from R4). Block = 64 rows x 32-col half.
// ---------------------------------------------------------------------------
__global__ __launch_bounds__(256) void proj_kernel(
    const float* __restrict__ x, const unsigned short* __restrict__ Wt,
    unsigned short* __restrict__ qw, unsigned short* __restrict__ kw,
    unsigned short* __restrict__ vT)
{
    __shared__ char LDSx[2][8192];
    __shared__ char LDSb[2][6144];

    const int tid = threadIdx.x;
    const int w = tid >> 6, l = tid & 63;
    const int xr = l & 15, lg = l >> 4;
    const int rb = blockIdx.x & 255, ch = blockIdx.x >> 8;
    const int row0 = rb * 64;

    const char* xsrc = (const char*)x + (size_t)row0 * 4096;
    const char* Wtb = (const char*)Wt;

    const int xrow_l = l >> 3, xcb = (l & 7) * 16;
    const int brow_l = l >> 2, bcb = (l & 3) * 16;

    auto stage = [&](int nb, int s) {
        #pragma unroll
        for (int c = 0; c < 4; ++c) {
            const int ci = w + 4 * c;
            if (ci < 8) {
                const int row = ci * 8 + xrow_l;
                const int sw = (row & 7) << 4;
                gl_lds16(xsrc + (size_t)row * 4096 + (size_t)s * 128 + (xcb ^ sw),
                         LDSx[nb] + ci * 1024);
            } else if (ci < 14) {
                const int c8 = ci - 8;
                const int r = c8 * 16 + brow_l;
                const int sw = ((r >> 1) & 3) << 4;
                const int wtrow = (r >> 5) * 64 + ch * 32 + (r & 31);
                gl_lds16(Wtb + (size_t)wtrow * 2048 + (size_t)s * 64 + (bcb ^ sw),
                         LDSb[nb] + c8 * 1024);
            }
        }
    };

    f32x4 acc[3][2];
    #pragma unroll
    for (int m = 0; m < 3; ++m)
        #pragma unroll
        for (int tt = 0; tt < 2; ++tt) { f32x4 z = {0.f,0.f,0.f,0.f}; acc[m][tt] = z; }

    stage(0, 0);
    __syncthreads();

    const int Rw = w * 16 + xr;
    const int swx = (Rw & 7) << 4;

    for (int s = 0; s < 32; ++s) {
        const int pb = s & 1;
        if (s < 31) stage(pb ^ 1, s + 1);

        float4 va = *(const float4*)(LDSx[pb] + Rw * 128 + ((32 * lg) ^ swx));
        float4 vb = *(const float4*)(LDSx[pb] + Rw * 128 + ((32 * lg + 16) ^ swx));
        bf16x8 a;
        a[0] = (short)f2bf(va.x); a[1] = (short)f2bf(va.y);
        a[2] = (short)f2bf(va.z); a[3] = (short)f2bf(va.w);
        a[4] = (short)f2bf(vb.x); a[5] = (short)f2bf(vb.y);
        a[6] = (short)f2bf(vb.z); a[7] = (short)f2bf(vb.w);

        #pragma unroll
        for (int m = 0; m < 3; ++m)
            #pragma unroll
            for (int tt = 0; tt < 2; ++tt) {
                const int rB = m * 32 + tt * 16 + xr;
                bf16x8 bfr = *(const bf16x8*)(LDSb[pb] + rB * 64 +
                                ((16 * lg) ^ (((rB >> 1) & 3) << 4)));
                acc[m][tt] = __builtin_amdgcn_mfma_f32_16x16x32_bf16(a, bfr, acc[m][tt], 0, 0, 0);
            }
        __syncthreads();
    }

    const int bb = row0 >> 12;
    #pragma unroll
    for (int tt = 0; tt < 2; ++tt) {
        const int col = ch * 32 + tt * 16 + xr;
        unsigned short pv4[4];
        #pragma unroll
        for (int i = 0; i < 4; ++i) {
            const int grow = row0 + w * 16 + 4 * lg + i;
            qw[(size_t)grow * 64 + col] = f2bf(acc[0][tt][i]);
            kw[(size_t)grow * 64 + col] = f2bf(acc[1][tt][i]);
            pv4[i] = f2bf(acc[2][tt][i]);
        }
        const int lr0 = (row0 & 4095) + w * 16 + 4 * lg;
        *(uint2*)&vT[((size_t)bb * 64 + col) * 4096 + lr0] = *(const uint2*)pv4;
    }
}

// ---------------------------------------------------------------------------
// Kernel 2: flash attention, swapped-operand (S^T / O^T) + XOR-swizzled LDS.
// grid (qb=64, chunk=8, b=4); chunk = 512 keys = 8 tiles of 64.
// Each lane owns ONE q-row: softmax reductions are in-lane + 2 shfl_xor.
// ---------------------------------------------------------------------------
__global__ __launch_bounds__(256) void attn_kernel(
    const unsigned short* __restrict__ qw, const unsigned short* __restrict__ kw,
    const unsigned short* __restrict__ vT,
    unsigned short* __restrict__ POb, float* __restrict__ Pm, float* __restrict__ Pl)
{
    __shared__ __align__(16) unsigned short Kb[2][4096];   // [key][d], swizzled
    __shared__ __align__(16) unsigned short Vb[2][4096];   // [d][key], swizzled
    __shared__ __align__(16) unsigned short Ps[4][16][72]; // [qrow][key]

    const int qb = blockIdx.x;     // q block (64 rows)
    const int c  = blockIdx.y;     // key chunk
    const int b  = blockIdx.z;
    if (c * 8 > qb) return;

    const int tid = threadIdx.x;
    const int w = tid >> 6, l = tid & 63;
    const int xr = l & 15, g = l >> 4;

    const int t0 = c * 8;
    const int rem = qb + 1 - t0;
    const int tcnt = rem < 8 ? rem : 8;
    const size_t base = (size_t)b * 4096;
    const int qrow = qb * 64 + w * 16;          // wave's first q-row (local)
    const int myrow = qrow + xr;                // this lane's q-row

    bf16x8 aq[2];
    #pragma unroll
    for (int h = 0; h < 2; ++h)
        aq[h] = *(const bf16x8*)(qw + (base + myrow) * 64 + 32 * h + 8 * g);

    // staging: linear LDS dest, inverse-swizzled global source (rule 21)
    const int wo0 = w * 2048, wo1 = wo0 + 1024;
    const int o0 = wo0 + 16 * l, o1 = wo1 + 16 * l;
    const int k0sw = (o0 & ~127) | ((o0 & 127) ^ (((o0 >> 7) & 7) << 4));
    const int k1sw = (o1 & ~127) | ((o1 & 127) ^ (((o1 >> 7) & 7) << 4));
    const size_t v0sw = (size_t)(o0 >> 7) * 8192 + ((o0 & 127) ^ (((o0 >> 7) & 7) << 4));
    const size_t v1sw = (size_t)(o1 >> 7) * 8192 + ((o1 & 127) ^ (((o1 >> 7) & 7) << 4));
    const char* kwb  = (const char*)kw + base * 128;
    const char* vtb0 = (const char*)vT + (size_t)b * 64 * 8192;

    auto stage = [&](int bi, int it) {
        const char* kt = kwb + (size_t)it * 8192;
        gl_lds16(kt + k0sw, (char*)Kb[bi] + wo0);
        gl_lds16(kt + k1sw, (char*)Kb[bi] + wo1);
        const char* vt = vtb0 + (size_t)it * 128;
        gl_lds16(vt + v0sw, (char*)Vb[bi] + wo0);
        gl_lds16(vt + v1sw, (char*)Vb[bi] + wo1);
    };

    f32x4 accO[4];
    #pragma unroll
    for (int t = 0; t < 4; ++t) { f32x4 z = {0.f,0.f,0.f,0.f}; accO[t] = z; }
    float mrow = -1e30f, lsum = 0.f;

    const int swz = (xr & 7) << 4;
    char* const psbase = (char*)&Ps[w][xr][0];

    stage(0, t0);
    __syncthreads();

    for (int tt = 0; tt < tcnt; ++tt) {
        const int it = t0 + tt;
        const int bi = tt & 1;
        if (tt + 1 < tcnt) stage(bi ^ 1, it + 1);

        // S^T = K Q^T : lane holds q-row = xr, keys 16t+4g+i
        const char* kbase = (const char*)Kb[bi];
        f32x4 s[4];
        __builtin_amdgcn_s_setprio(1);
        #pragma unroll
        for (int t = 0; t < 4; ++t) {
            f32x4 z = {0.f,0.f,0.f,0.f};
            s[t] = z;
            #pragma unroll
            for (int h = 0; h < 2; ++h) {
                bf16x8 ak = *(const bf16x8*)(kbase + (xr + 16 * t) * 128 + ((64 * h + 16 * g) ^ swz));
                s[t] = __builtin_amdgcn_mfma_f32_16x16x32_bf16(ak, aq[h], s[t], 0, 0, 0);
            }
        }
        __builtin_amdgcn_s_setprio(0);

        if (it == qb) {   // diagonal tile: causal mask
            #pragma unroll
            for (int t = 0; t < 4; ++t)
                #pragma unroll
                for (int i = 0; i < 4; ++i) {
                    const int key = it * 64 + 16 * t + 4 * g + i;
                    if (key > myrow) s[t][i] = -1e30f;
                }
        }

        // in-lane row max over 16 keys, then reduce across 4 g-groups
        float tm;
        {
            float m0 = fmaxf(fmaxf(s[0][0], s[0][1]), fmaxf(s[0][2], s[0][3]));
            float m1 = fmaxf(fmaxf(s[1][0], s[1][1]), fmaxf(s[1][2], s[1][3]));
            float m2 = fmaxf(fmaxf(s[2][0], s[2][1]), fmaxf(s[2][2], s[2][3]));
            float m3 = fmaxf(fmaxf(s[3][0], s[3][1]), fmaxf(s[3][2], s[3][3]));
            tm = fmaxf(fmaxf(m0, m1), fmaxf(m2, m3));
        }
        tm = fmaxf(tm, __shfl_xor(tm, 16, 64));
        tm = fmaxf(tm, __shfl_xor(tm, 32, 64));

        const float mnew = fmaxf(mrow, tm);
        const float fac = exp2f(mrow - mnew);

        #pragma unroll
        for (int t = 0; t < 4; ++t)
            #pragma unroll
            for (int i = 0; i < 4; ++i)
                s[t][i] = exp2f(s[t][i] - mnew);

        float psum;
        {
            float a0 = (s[0][0] + s[0][1]) + (s[0][2] + s[0][3]);
            float a1 = (s[1][0] + s[1][1]) + (s[1][2] + s[1][3]);
            float a2 = (s[2][0] + s[2][1]) + (s[2][2] + s[2][3]);
            float a3 = (s[3][0] + s[3][1]) + (s[3][2] + s[3][3]);
            psum = (a0 + a1) + (a2 + a3);
        }
        psum += __shfl_xor(psum, 16, 64);
        psum += __shfl_xor(psum, 32, 64);

        lsum = lsum * fac + psum;
        mrow = mnew;
        #pragma unroll
        for (int t = 0; t < 4; ++t)
            #pragma unroll
            for (int i = 0; i < 4; ++i) accO[t][i] *= fac;

        // P -> LDS (bf16, packed b64 writes; row = lane's q-row)
        #pragma unroll
        for (int t = 0; t < 4; ++t) {
            uint2 uu;
            uu.x = cvtpk(s[t][0], s[t][1]);
            uu.y = cvtpk(s[t][2], s[t][3]);
            *(uint2*)(psbase + 32 * t + 8 * g) = uu;
        }

        // O^T += V^T P^T : lane holds q-row = xr, d = 16t+4g+i
        bf16x8 pa[2];
        #pragma unroll
        for (int h = 0; h < 2; ++h)
            pa[h] = *(const bf16x8*)(psbase + 16 * g + 64 * h);
        const char* vbase = (const char*)Vb[bi];
        __builtin_amdgcn_s_setprio(1);
        #pragma unroll
        for (int t = 0; t < 4; ++t)
            #pragma unroll
            for (int h = 0; h < 2; ++h) {
                bf16x8 av = *(const bf16x8*)(vbase + (16 * t + xr) * 128 + ((64 * h + 16 * g) ^ swz));
                accO[t] = __builtin_amdgcn_mfma_f32_16x16x32_bf16(av, pa[h], accO[t], 0, 0, 0);
            }
        __builtin_amdgcn_s_setprio(0);

        __syncthreads();
    }

    // epilogue: unnormalized O (bf16) + m, l
    const size_t prow = (size_t)(b * 8 + c) * 4096 + qrow;
    #pragma unroll
    for (int t = 0; t < 4; ++t) {
        uint2 uu;
        uu.x = cvtpk(accO[t][0], accO[t][1]);
        uu.y = cvtpk(accO[t][2], accO[t][3]);
        *(uint2*)&POb[(prow + xr) * 64 + 16 * t + 4 * g] = uu;
    }
    if (l < 16) {
        Pm[prow + l] = mrow;
        Pl[prow + l] = lsum;
    }
}

// ---------------------------------------------------------------------------
// Kernel 3: merge <=8 chunk partials per row -> out
// ---------------------------------------------------------------------------
__global__ __launch_bounds__(256) void merge_kernel(
    const unsigned short* __restrict__ POb, const float* __restrict__ Pm,
    const float* __restrict__ Pl, float* __restrict__ out)
{
    const int gid = blockIdx.x * 256 + threadIdx.x;  // 0..65535
    const int r = gid >> 2;
    const int c0 = (gid & 3) * 16;
    const int b = r >> 12, lr = r & 4095;
    const int nc = (lr >> 9) + 1;

    float mv[8], lv[8];
    #pragma unroll
    for (int ci = 0; ci < 8; ++ci) {
        const bool act = ci < nc;
        mv[ci] = act ? Pm[(size_t)(b * 8 + ci) * 4096 + lr] : -1e30f;
        lv[ci] = act ? Pl[(size_t)(b * 8 + ci) * 4096 + lr] : 0.f;
    }
    float M = mv[0];
    #pragma unroll
    for (int ci = 1; ci < 8; ++ci) M = fmaxf(M, mv[ci]);
    float wgt[8], L = 0.f;
    #pragma unroll
    for (int ci = 0; ci < 8; ++ci) {
        wgt[ci] = exp2f(mv[ci] - M);
        L += wgt[ci] * lv[ci];
    }
    const float rL = 1.0f / L;

    float acc[16];
    #pragma unroll
    for (int j = 0; j < 16; ++j) acc[j] = 0.f;

    #pragma unroll
    for (int ci = 0; ci < 8; ++ci) {
        if (ci < nc) {
            const unsigned short* p = POb + ((size_t)(b * 8 + ci) * 4096 + lr) * 64 + c0;
            uint4 u0 = *(const uint4*)p;
            uint4 u1 = *(const uint4*)(p + 8);
            const unsigned int us[8] = {u0.x, u0.y, u0.z, u0.w, u1.x, u1.y, u1.z, u1.w};
            #pragma unroll
            for (int k = 0; k < 8; ++k) {
                const float flo = __builtin_bit_cast(float, us[k] << 16);
                const float fhi = __builtin_bit_cast(float, us[k] & 0xFFFF0000u);
                acc[2 * k]     += wgt[ci] * flo;
                acc[2 * k + 1] += wgt[ci] * fhi;
            }
        }
    }
    float* op = out + (size_t)r * 64 + c0;
    #pragma unroll
    for (int j = 0; j < 4; ++j) {
        float4 v;
        v.x = acc[4 * j]     * rL;
        v.y = acc[4 * j + 1] * rL;
        v.z = acc[4 * j + 2] * rL;
        v.w = acc[4 * j + 3] * rL;
        *(float4*)(op + 4 * j) = v;
    }
}

extern "C" void kernel_launch(void* const* d_in, const int* in_sizes, int n_in,
                              void* d_out, int out_size, void* d_ws, size_t ws_size,
                              hipStream_t stream) {
    const float* x  = (const float*)d_in[0];
    const float* Wk = (const float*)d_in[1];
    const float* Wq = (const float*)d_in[2];
    const float* Wv = (const float*)d_in[3];
    float* out = (float*)d_out;

    char* wsb = (char*)d_ws;
    unsigned short* POb = (unsigned short*)wsb;            // [32][4096][64] bf16 = 16MB
    float* Pm = (float*)(wsb + (size_t)17 * 1024 * 1024);  // [32][4096]
    float* Pl = Pm + (size_t)32 * 4096;
    unsigned short* Wt = (unsigned short*)(wsb + (size_t)24 * 1024 * 1024);
    unsigned short* qw = Wt + (size_t)3 * 64 * 1024;       // [16384][64]
    unsigned short* kw = qw + (size_t)16384 * 64;          // [16384][64]
    unsigned short* vT = kw + (size_t)16384 * 64;          // [4][64][4096]

    hipLaunchKernelGGL(wt_kernel, dim3(48), dim3(256), 0, stream, Wk, Wq, Wv, Wt);
    hipLaunchKernelGGL(proj_kernel, dim3(512), dim3(256), 0, stream, x, Wt, qw, kw, vT);
    hipLaunchKernelGGL(attn_kernel, dim3(64, 8, 4), dim3(256), 0, stream, qw, kw, vT, POb, Pm, Pl);
    hipLaunchKernelGGL(merge_kernel, dim3(256), dim3(256), 0, stream, POb, Pm, Pl, out);
}

// Round 6
// 77.172 us; speedup vs baseline: 4.7282x; 1.0321x over previous
//
#include <hip/hip_runtime.h>

typedef __attribute__((ext_vector_type(8))) short bf16x8;
typedef __attribute__((ext_vector_type(4))) float f32x4;

#define DI __device__ __forceinline__

DI unsigned short f2bf(float f) {
    unsigned int u = __builtin_bit_cast(unsigned int, f);
    u += 0x7fff + ((u >> 16) & 1);
    return (unsigned short)(u >> 16);
}

DI unsigned int cvtpk(float lo, float hi) {
    unsigned int r;
    asm("v_cvt_pk_bf16_f32 %0, %1, %2" : "=v"(r) : "v"(lo), "v"(hi));
    return r;
}

DI void gl_lds16(const void* g, void* l) {
    __builtin_amdgcn_global_load_lds(
        (const __attribute__((address_space(1))) unsigned int*)g,
        (__attribute__((address_space(3))) unsigned int*)l, 16, 0, 0);
}

#define WAITCNT(n) asm volatile("s_waitcnt vmcnt(" #n ")" ::: "memory")

// ---------------------------------------------------------------------------
// Kernel 0: Wt[m][c][k] = W_m[k][c] * scale_m (bf16). m: 0=q(scaled),1=k,2=v
// ---------------------------------------------------------------------------
__global__ __launch_bounds__(256) void wt_kernel(
    const float* __restrict__ Wk, const float* __restrict__ Wq,
    const float* __restrict__ Wv, unsigned short* __restrict__ Wt)
{
    __shared__ float ws[64][65];
    const int m = blockIdx.x >> 4, kc = blockIdx.x & 15;
    const float* W = (m == 0) ? Wq : (m == 1) ? Wk : Wv;
    const float scale = (m == 0) ? 0.18033688011112042f : 1.0f;
    const int tid = threadIdx.x;
    #pragma unroll
    for (int r = 0; r < 16; ++r) {
        int idx = r * 256 + tid;
        ws[idx >> 6][idx & 63] = W[(kc * 64 + (idx >> 6)) * 64 + (idx & 63)] * scale;
    }
    __syncthreads();
    const int c = tid >> 2, k4 = (tid & 3) * 16;
    bf16x8 o0, o1;
    #pragma unroll
    for (int j = 0; j < 8; ++j) o0[j] = (short)f2bf(ws[k4 + j][c]);
    #pragma unroll
    for (int j = 0; j < 8; ++j) o1[j] = (short)f2bf(ws[k4 + 8 + j][c]);
    unsigned short* dst = Wt + ((size_t)m * 64 + c) * 1024 + kc * 64 + k4;
    *(bf16x8*)dst = o0;
    *(bf16x8*)(dst + 8) = o1;
}

// ---------------------------------------------------------------------------
// Kernel 1: proj. 4-deep LDS pipeline, counted vmcnt, raw barriers.
// Block = 64 rows x 32-col half; grid 512.
// ---------------------------------------------------------------------------
__global__ __launch_bounds__(256) void proj_kernel(
    const float* __restrict__ x, const unsigned short* __restrict__ Wt,
    unsigned short* __restrict__ qw, unsigned short* __restrict__ kw,
    unsigned short* __restrict__ vT)
{
    __shared__ char LDSx[4][8192];   // x tile [64 rows][32 f32], swizzled
    __shared__ char LDSb[4][6144];   // B tile [96 rows][32 bf16], swizzled

    const int tid = threadIdx.x;
    const int w = tid >> 6, l = tid & 63;
    const int xr = l & 15, lg = l >> 4;
    const int rb = blockIdx.x & 255, ch = blockIdx.x >> 8;
    const int row0 = rb * 64;

    const char* xsrc = (const char*)x + (size_t)row0 * 4096;
    const char* Wtb = (const char*)Wt;

    const int xrow_l = l >> 3, xcb = (l & 7) * 16;
    const int brow_l = l >> 2, bcb = (l & 3) * 16;

    // waves 0,1: 4 loads/stage; waves 2,3: 3 loads/stage
    auto stage = [&](int nb, int s) {
        #pragma unroll
        for (int c = 0; c < 4; ++c) {
            const int ci = w + 4 * c;
            if (ci < 8) {
                const int row = ci * 8 + xrow_l;
                const int sw = (row & 7) << 4;
                gl_lds16(xsrc + (size_t)row * 4096 + (size_t)s * 128 + (xcb ^ sw),
                         LDSx[nb] + ci * 1024);
            } else if (ci < 14) {
                const int c8 = ci - 8;
                const int r = c8 * 16 + brow_l;
                const int sw = ((r >> 1) & 3) << 4;
                const int wtrow = (r >> 5) * 64 + ch * 32 + (r & 31);
                gl_lds16(Wtb + (size_t)wtrow * 2048 + (size_t)s * 64 + (bcb ^ sw),
                         LDSb[nb] + c8 * 1024);
            }
        }
    };

    f32x4 acc[3][2];
    #pragma unroll
    for (int m = 0; m < 3; ++m)
        #pragma unroll
        for (int tt = 0; tt < 2; ++tt) { f32x4 z = {0.f,0.f,0.f,0.f}; acc[m][tt] = z; }

    const int Rw = w * 16 + xr;
    const int swx = (Rw & 7) << 4;

    auto compute = [&](int s) {
        const int pb = s & 3;
        float4 va = *(const float4*)(LDSx[pb] + Rw * 128 + ((32 * lg) ^ swx));
        float4 vb = *(const float4*)(LDSx[pb] + Rw * 128 + ((32 * lg + 16) ^ swx));
        bf16x8 a;
        a[0] = (short)f2bf(va.x); a[1] = (short)f2bf(va.y);
        a[2] = (short)f2bf(va.z); a[3] = (short)f2bf(va.w);
        a[4] = (short)f2bf(vb.x); a[5] = (short)f2bf(vb.y);
        a[6] = (short)f2bf(vb.z); a[7] = (short)f2bf(vb.w);
        __builtin_amdgcn_s_setprio(1);
        #pragma unroll
        for (int m = 0; m < 3; ++m)
            #pragma unroll
            for (int tt = 0; tt < 2; ++tt) {
                const int rB = m * 32 + tt * 16 + xr;
                bf16x8 bfr = *(const bf16x8*)(LDSb[pb] + rB * 64 +
                                ((16 * lg) ^ (((rB >> 1) & 3) << 4)));
                acc[m][tt] = __builtin_amdgcn_mfma_f32_16x16x32_bf16(a, bfr, acc[m][tt], 0, 0, 0);
            }
        __builtin_amdgcn_s_setprio(0);
    };

    stage(0, 0); stage(1, 1); stage(2, 2);

    for (int s = 0; s < 30; ++s) {
        // wait until only stages s+1, s+2 outstanding -> stage(s) complete
        if (w < 2) WAITCNT(8); else WAITCNT(6);
        __builtin_amdgcn_sched_barrier(0);
        __builtin_amdgcn_s_barrier();
        if (s < 29) stage((s + 3) & 3, s + 3);   // after barrier: no WAR race
        compute(s);
    }
    WAITCNT(0);
    __builtin_amdgcn_sched_barrier(0);
    __builtin_amdgcn_s_barrier();
    compute(30);
    compute(31);

    const int bb = row0 >> 12;
    #pragma unroll
    for (int tt = 0; tt < 2; ++tt) {
        const int col = ch * 32 + tt * 16 + xr;
        unsigned short pv4[4];
        #pragma unroll
        for (int i = 0; i < 4; ++i) {
            const int grow = row0 + w * 16 + 4 * lg + i;
            qw[(size_t)grow * 64 + col] = f2bf(acc[0][tt][i]);
            kw[(size_t)grow * 64 + col] = f2bf(acc[1][tt][i]);
            pv4[i] = f2bf(acc[2][tt][i]);
        }
        const int lr0 = (row0 & 4095) + w * 16 + 4 * lg;
        *(uint2*)&vT[((size_t)bb * 64 + col) * 4096 + lr0] = *(const uint2*)pv4;
    }
}

// ---------------------------------------------------------------------------
// Kernel 2: flash attention, swapped-operand, 4-deep pipeline, counted vmcnt.
// grid (qb=64, chunk=8, b=4); chunk = 512 keys = 8 tiles of 64.
// ---------------------------------------------------------------------------
__global__ __launch_bounds__(256) void attn_kernel(
    const unsigned short* __restrict__ qw, const unsigned short* __restrict__ kw,
    const unsigned short* __restrict__ vT,
    unsigned short* __restrict__ POb, float* __restrict__ Pm, float* __restrict__ Pl)
{
    __shared__ __align__(16) unsigned short Kb[4][4096];   // [key][d], swizzled
    __shared__ __align__(16) unsigned short Vb[4][4096];   // [d][key], swizzled
    __shared__ __align__(16) unsigned short Ps[4][16][72]; // [qrow][key]

    const int qb = blockIdx.x;
    const int c  = blockIdx.y;
    const int b  = blockIdx.z;
    if (c * 8 > qb) return;

    const int tid = threadIdx.x;
    const int w = tid >> 6, l = tid & 63;
    const int xr = l & 15, g = l >> 4;

    const int t0 = c * 8;
    const int rem0 = qb + 1 - t0;
    const int tcnt = rem0 < 8 ? rem0 : 8;
    const size_t base = (size_t)b * 4096;
    const int qrow = qb * 64 + w * 16;
    const int myrow = qrow + xr;

    bf16x8 aq[2];
    #pragma unroll
    for (int h = 0; h < 2; ++h)
        aq[h] = *(const bf16x8*)(qw + (base + myrow) * 64 + 32 * h + 8 * g);

    const int wo0 = w * 2048, wo1 = wo0 + 1024;
    const int o0 = wo0 + 16 * l, o1 = wo1 + 16 * l;
    const int k0sw = (o0 & ~127) | ((o0 & 127) ^ (((o0 >> 7) & 7) << 4));
    const int k1sw = (o1 & ~127) | ((o1 & 127) ^ (((o1 >> 7) & 7) << 4));
    const size_t v0sw = (size_t)(o0 >> 7) * 8192 + ((o0 & 127) ^ (((o0 >> 7) & 7) << 4));
    const size_t v1sw = (size_t)(o1 >> 7) * 8192 + ((o1 & 127) ^ (((o1 >> 7) & 7) << 4));
    const char* kwb  = (const char*)kw + base * 128;
    const char* vtb0 = (const char*)vT + (size_t)b * 64 * 8192;

    auto stage = [&](int bi, int it) {   // exactly 4 loads per wave
        const char* kt = kwb + (size_t)it * 8192;
        gl_lds16(kt + k0sw, (char*)Kb[bi] + wo0);
        gl_lds16(kt + k1sw, (char*)Kb[bi] + wo1);
        const char* vt = vtb0 + (size_t)it * 128;
        gl_lds16(vt + v0sw, (char*)Vb[bi] + wo0);
        gl_lds16(vt + v1sw, (char*)Vb[bi] + wo1);
    };

    f32x4 accO[4];
    #pragma unroll
    for (int t = 0; t < 4; ++t) { f32x4 z = {0.f,0.f,0.f,0.f}; accO[t] = z; }
    float mrow = -1e30f, lsum = 0.f;

    const int swz = (xr & 7) << 4;
    char* const psbase = (char*)&Ps[w][xr][0];

    stage(0, t0);
    if (tcnt > 1) stage(1, t0 + 1);
    if (tcnt > 2) stage(2, t0 + 2);

    for (int tt = 0; tt < tcnt; ++tt) {
        const int it = t0 + tt;
        const int bi = tt & 3;
        const int ra = tcnt - 1 - tt;
        if (ra >= 2)      WAITCNT(8);
        else if (ra == 1) WAITCNT(4);
        else              WAITCNT(0);
        __builtin_amdgcn_sched_barrier(0);
        __builtin_amdgcn_s_barrier();
        if (tt + 3 < tcnt) stage((tt + 3) & 3, it + 3);

        // S^T = K Q^T : lane holds q-row = xr, keys 16t+4g+i
        const char* kbase = (const char*)Kb[bi];
        f32x4 s[4];
        __builtin_amdgcn_s_setprio(1);
        #pragma unroll
        for (int t = 0; t < 4; ++t) {
            f32x4 z = {0.f,0.f,0.f,0.f};
            s[t] = z;
            #pragma unroll
            for (int h = 0; h < 2; ++h) {
                bf16x8 ak = *(const bf16x8*)(kbase + (xr + 16 * t) * 128 + ((64 * h + 16 * g) ^ swz));
                s[t] = __builtin_amdgcn_mfma_f32_16x16x32_bf16(ak, aq[h], s[t], 0, 0, 0);
            }
        }
        __builtin_amdgcn_s_setprio(0);

        if (it == qb) {
            #pragma unroll
            for (int t = 0; t < 4; ++t)
                #pragma unroll
                for (int i = 0; i < 4; ++i) {
                    const int key = it * 64 + 16 * t + 4 * g + i;
                    if (key > myrow) s[t][i] = -1e30f;
                }
        }

        float tm;
        {
            float m0 = fmaxf(fmaxf(s[0][0], s[0][1]), fmaxf(s[0][2], s[0][3]));
            float m1 = fmaxf(fmaxf(s[1][0], s[1][1]), fmaxf(s[1][2], s[1][3]));
            float m2 = fmaxf(fmaxf(s[2][0], s[2][1]), fmaxf(s[2][2], s[2][3]));
            float m3 = fmaxf(fmaxf(s[3][0], s[3][1]), fmaxf(s[3][2], s[3][3]));
            tm = fmaxf(fmaxf(m0, m1), fmaxf(m2, m3));
        }
        tm = fmaxf(tm, __shfl_xor(tm, 16, 64));
        tm = fmaxf(tm, __shfl_xor(tm, 32, 64));

        const float mnew = fmaxf(mrow, tm);
        const float fac = exp2f(mrow - mnew);

        #pragma unroll
        for (int t = 0; t < 4; ++t)
            #pragma unroll
            for (int i = 0; i < 4; ++i)
                s[t][i] = exp2f(s[t][i] - mnew);

        float psum;
        {
            float a0 = (s[0][0] + s[0][1]) + (s[0][2] + s[0][3]);
            float a1 = (s[1][0] + s[1][1]) + (s[1][2] + s[1][3]);
            float a2 = (s[2][0] + s[2][1]) + (s[2][2] + s[2][3]);
            float a3 = (s[3][0] + s[3][1]) + (s[3][2] + s[3][3]);
            psum = (a0 + a1) + (a2 + a3);
        }
        psum += __shfl_xor(psum, 16, 64);
        psum += __shfl_xor(psum, 32, 64);

        lsum = lsum * fac + psum;
        mrow = mnew;
        #pragma unroll
        for (int t = 0; t < 4; ++t)
            #pragma unroll
            for (int i = 0; i < 4; ++i) accO[t][i] *= fac;

        #pragma unroll
        for (int t = 0; t < 4; ++t) {
            uint2 uu;
            uu.x = cvtpk(s[t][0], s[t][1]);
            uu.y = cvtpk(s[t][2], s[t][3]);
            *(uint2*)(psbase + 32 * t + 8 * g) = uu;
        }

        bf16x8 pa[2];
        #pragma unroll
        for (int h = 0; h < 2; ++h)
            pa[h] = *(const bf16x8*)(psbase + 16 * g + 64 * h);
        const char* vbase = (const char*)Vb[bi];
        __builtin_amdgcn_s_setprio(1);
        #pragma unroll
        for (int t = 0; t < 4; ++t)
            #pragma unroll
            for (int h = 0; h < 2; ++h) {
                bf16x8 av = *(const bf16x8*)(vbase + (16 * t + xr) * 128 + ((64 * h + 16 * g) ^ swz));
                accO[t] = __builtin_amdgcn_mfma_f32_16x16x32_bf16(av, pa[h], accO[t], 0, 0, 0);
            }
        __builtin_amdgcn_s_setprio(0);
    }

    const size_t prow = (size_t)(b * 8 + c) * 4096 + qrow;
    #pragma unroll
    for (int t = 0; t < 4; ++t) {
        uint2 uu;
        uu.x = cvtpk(accO[t][0], accO[t][1]);
        uu.y = cvtpk(accO[t][2], accO[t][3]);
        *(uint2*)&POb[(prow + xr) * 64 + 16 * t + 4 * g] = uu;
    }
    if (l < 16) {
        Pm[prow + l] = mrow;
        Pl[prow + l] = lsum;
    }
}

// ---------------------------------------------------------------------------
// Kernel 3: merge <=8 chunk partials per row -> out
// ---------------------------------------------------------------------------
__global__ __launch_bounds__(256) void merge_kernel(
    const unsigned short* __restrict__ POb, const float* __restrict__ Pm,
    const float* __restrict__ Pl, float* __restrict__ out)
{
    const int gid = blockIdx.x * 256 + threadIdx.x;
    const int r = gid >> 2;
    const int c0 = (gid & 3) * 16;
    const int b = r >> 12, lr = r & 4095;
    const int nc = (lr >> 9) + 1;

    float mv[8], lv[8];
    #pragma unroll
    for (int ci = 0; ci < 8; ++ci) {
        const bool act = ci < nc;
        mv[ci] = act ? Pm[(size_t)(b * 8 + ci) * 4096 + lr] : -1e30f;
        lv[ci] = act ? Pl[(size_t)(b * 8 + ci) * 4096 + lr] : 0.f;
    }
    float M = mv[0];
    #pragma unroll
    for (int ci = 1; ci < 8; ++ci) M = fmaxf(M, mv[ci]);
    float wgt[8], L = 0.f;
    #pragma unroll
    for (int ci = 0; ci < 8; ++ci) {
        wgt[ci] = exp2f(mv[ci] - M);
        L += wgt[ci] * lv[ci];
    }
    const float rL = 1.0f / L;

    float acc[16];
    #pragma unroll
    for (int j = 0; j < 16; ++j) acc[j] = 0.f;

    #pragma unroll
    for (int ci = 0; ci < 8; ++ci) {
        if (ci < nc) {
            const unsigned short* p = POb + ((size_t)(b * 8 + ci) * 4096 + lr) * 64 + c0;
            uint4 u0 = *(const uint4*)p;
            uint4 u1 = *(const uint4*)(p + 8);
            const unsigned int us[8] = {u0.x, u0.y, u0.z, u0.w, u1.x, u1.y, u1.z, u1.w};
            #pragma unroll
            for (int k = 0; k < 8; ++k) {
                const float flo = __builtin_bit_cast(float, us[k] << 16);
                const float fhi = __builtin_bit_cast(float, us[k] & 0xFFFF0000u);
                acc[2 * k]     += wgt[ci] * flo;
                acc[2 * k + 1] += wgt[ci] * fhi;
            }
        }
    }
    float* op = out + (size_t)r * 64 + c0;
    #pragma unroll
    for (int j = 0; j < 4; ++j) {
        float4 v;
        v.x = acc[4 * j]     * rL;
        v.y = acc[4 * j + 1] * rL;
        v.z = acc[4 * j + 2] * rL;
        v.w = acc[4 * j + 3] * rL;
        *(float4*)(op + 4 * j) = v;
    }
}

extern "C" void kernel_launch(void* const* d_in, const int* in_sizes, int n_in,
                              void* d_out, int out_size, void* d_ws, size_t ws_size,
                              hipStream_t stream) {
    const float* x  = (const float*)d_in[0];
    const float* Wk = (const float*)d_in[1];
    const float* Wq = (const float*)d_in[2];
    const float* Wv = (const float*)d_in[3];
    float* out = (float*)d_out;

    char* wsb = (char*)d_ws;
    unsigned short* POb = (unsigned short*)wsb;            // [32][4096][64] bf16 = 16MB
    float* Pm = (float*)(wsb + (size_t)17 * 1024 * 1024);  // [32][4096]
    float* Pl = Pm + (size_t)32 * 4096;
    unsigned short* Wt = (unsigned short*)(wsb + (size_t)24 * 1024 * 1024);
    unsigned short* qw = Wt + (size_t)3 * 64 * 1024;       // [16384][64]
    unsigned short* kw = qw + (size_t)16384 * 64;          // [16384][64]
    unsigned short* vT = kw + (size_t)16384 * 64;          // [4][64][4096]

    hipLaunchKernelGGL(wt_kernel, dim3(48), dim3(256), 0, stream, Wk, Wq, Wv, Wt);
    hipLaunchKernelGGL(proj_kernel, dim3(512), dim3(256), 0, stream, x, Wt, qw, kw, vT);
    hipLaunchKernelGGL(attn_kernel, dim3(64, 8, 4), dim3(256), 0, stream, qw, kw, vT, POb, Pm, Pl);
    hipLaunchKernelGGL(merge_kernel, dim3(256), dim3(256), 0, stream, POb, Pm, Pl, out);
}